// Round 11
// baseline (1062.830 us; speedup 1.0000x reference)
//
#include <hip/hip_runtime.h>
#include <hip/hip_bf16.h>
#include <hip/hip_fp16.h>

#define N_NODES_C 100000
#define N_EDGES_C 500000
#define N_REL_C 6
#define IN_DIM_C 64
#define HID_C 128
#define HEADS_C 4
#define CPH_C 32
#define N_GRAPHS_C 1024
#define NBLK_SCAN 391   // ceil(100000/256)
#define SH_PAD 8        // LDS transpose row pad (halves): 2-way banks, 16B aligned

typedef _Float16 f16x8 __attribute__((ext_vector_type(8)));
typedef float f32x4 __attribute__((ext_vector_type(4)));

// ========== CSR hist+rank, fused with fp32->fp16 converts ==========
__global__ __launch_bounds__(256) void hist_rank_convert_kernel(
    const int* __restrict__ ei, int* __restrict__ cnt, int* __restrict__ rank,
    const float* __restrict__ x, __half* __restrict__ xh,
    const float* __restrict__ W1, const float* __restrict__ W2,
    __half* __restrict__ Wt1, __half* __restrict__ Wt2) {
    int i = blockIdx.x * 256 + threadIdx.x;
    if (i < N_NODES_C * IN_DIM_C / 4) {
        float4 v = ((const float4*)x)[i];
        union { __half h[4]; uint2 u; } u;
        u.h[0] = __float2half(v.x); u.h[1] = __float2half(v.y);
        u.h[2] = __float2half(v.z); u.h[3] = __float2half(v.w);
        ((uint2*)xh)[i] = u.u;
    }
    if (i < N_REL_C * IN_DIM_C * HID_C) {
        int r = i / (IN_DIM_C * HID_C);
        int rem = i - r * (IN_DIM_C * HID_C);
        int k = rem / HID_C, n = rem - k * HID_C;
        Wt1[(size_t)r * HID_C * IN_DIM_C + n * IN_DIM_C + k] = __float2half(W1[i]);
    }
    if (i < N_REL_C * HID_C * HID_C) {
        int r = i / (HID_C * HID_C);
        int rem = i - r * (HID_C * HID_C);
        int k = rem / HID_C, n = rem - k * HID_C;
        Wt2[(size_t)r * HID_C * HID_C + n * HID_C + k] = __float2half(W2[i]);
    }
    if (i < N_REL_C * N_EDGES_C) {
        int r = i / N_EDGES_C;
        int e = i - r * N_EDGES_C;
        int dst = ei[(size_t)r * 2 * N_EDGES_C + N_EDGES_C + e];
        rank[i] = atomicAdd(&cnt[r * N_NODES_C + dst], 1);
    }
}

// per-256-block exclusive scan; bsums[r][b] = block total
__global__ __launch_bounds__(256) void scan1_kernel(const int* __restrict__ cnt,
                                                    int* __restrict__ rowptr,
                                                    int* __restrict__ blocksums) {
    int r = blockIdx.y, b = blockIdx.x, t = threadIdx.x;
    int idx = b * 256 + t;
    int v = (idx < N_NODES_C) ? cnt[r * N_NODES_C + idx] : 0;
    int orig = v;
    int lane = t & 63, w = t >> 6;
#pragma unroll
    for (int off = 1; off < 64; off <<= 1) {
        int n = __shfl_up(v, off);
        if (lane >= off) v += n;
    }
    __shared__ int wt[4];
    if (lane == 63) wt[w] = v;
    __syncthreads();
    int add = 0;
    for (int i = 0; i < w; i++) add += wt[i];
    v += add;
    if (idx < N_NODES_C) rowptr[(size_t)r * (N_NODES_C + 1) + idx] = v - orig;
    if (t == 255) blocksums[r * NBLK_SCAN + b] = v;
}

// scan block sums -> exclusive prefixes (final rowptr = rowptrP + bsums[b])
__global__ __launch_bounds__(512) void scan2_kernel(int* __restrict__ blocksums) {
    int r = blockIdx.x, t = threadIdx.x;
    int v = (t < NBLK_SCAN) ? blocksums[r * NBLK_SCAN + t] : 0;
    int orig = v;
    int lane = t & 63, w = t >> 6;
#pragma unroll
    for (int off = 1; off < 64; off <<= 1) {
        int n = __shfl_up(v, off);
        if (lane >= off) v += n;
    }
    __shared__ int wt[8];
    if (lane == 63) wt[w] = v;
    __syncthreads();
    int add = 0;
    for (int i = 0; i < w; i++) add += wt[i];
    v += add;
    if (t < NBLK_SCAN) blocksums[r * NBLK_SCAN + t] = v - orig;
}

// atomic-free scatter; nontemporal scattered stores (no L2 line RFO/bounce)
__global__ __launch_bounds__(256) void scatter_kernel(const int* __restrict__ ei,
                                                      const int* __restrict__ rowptrP,
                                                      const int* __restrict__ bsums,
                                                      const int* __restrict__ rank,
                                                      int* __restrict__ srcids) {
    int i = blockIdx.x * 256 + threadIdx.x;
    if (i >= N_REL_C * N_EDGES_C) return;
    int r = i / N_EDGES_C;
    int e = i - r * N_EDGES_C;
    int src = __builtin_nontemporal_load(ei + (size_t)r * 2 * N_EDGES_C + e);
    int dst = __builtin_nontemporal_load(ei + (size_t)r * 2 * N_EDGES_C + N_EDGES_C + e);
    int rk  = __builtin_nontemporal_load(rank + i);
    int base = rowptrP[(size_t)r * (N_NODES_C + 1) + dst] + bsums[r * NBLK_SCAN + (dst >> 8)];
    __builtin_nontemporal_store(src, srcids + (size_t)r * N_EDGES_C + base + rk);
}

// ================= fp16 MFMA GEMM + attn-logit epilogue =================
template <int K>
__global__ __launch_bounds__(256) void gemm_mfma_kernel(
    const __half* __restrict__ Xh, const __half* __restrict__ Wtbase,
    __half* __restrict__ Hbase,
    const float* __restrict__ asbase, const float* __restrict__ adbase,
    float* __restrict__ alsbase, float* __restrict__ aldbase) {
    __shared__ _Float16 sh[4][16][HID_C + SH_PAD];
    const int slot = blockIdx.y;
    const __half* Wt = Wtbase + (size_t)slot * HID_C * K;
    __half* H = Hbase + (size_t)slot * N_NODES_C * HID_C;
    const int wave = threadIdx.x >> 6, lane = threadIdx.x & 63;
    const int r0 = blockIdx.x * 64 + wave * 16;
    const int m = lane & 15, quad = lane >> 4;
    int arow = r0 + m;
    if (arow > N_NODES_C - 1) arow = N_NODES_C - 1;
    const __half* ap = Xh + (size_t)arow * K + quad * 8;
    const __half* bp = Wt + (size_t)m * K + quad * 8;

    f32x4 acc[8];
#pragma unroll
    for (int t = 0; t < 8; t++) acc[t] = (f32x4){0.f, 0.f, 0.f, 0.f};

#pragma unroll
    for (int kc = 0; kc < K; kc += 32) {
        f16x8 a = *(const f16x8*)(ap + kc);
#pragma unroll
        for (int t = 0; t < 8; t++) {
            f16x8 b = *(const f16x8*)(bp + (size_t)t * 16 * K + kc);
            acc[t] = __builtin_amdgcn_mfma_f32_16x16x32_f16(a, b, acc[t], 0, 0, 0);
        }
    }

    // transpose C-layout -> row-major via LDS (same-wave: no barrier needed)
#pragma unroll
    for (int t = 0; t < 8; t++)
#pragma unroll
        for (int i = 0; i < 4; i++)
            sh[wave][quad * 4 + i][t * 16 + m] = (_Float16)acc[t][i];
#pragma unroll
    for (int p = 0; p < 4; p++) {
        int idx = p * 512 + lane * 8;
        int row = idx >> 7;
        int col = idx & 127;
        int R = r0 + row;
        if (R < N_NODES_C)
            *(uint4*)(H + (size_t)R * HID_C + col) = *(const uint4*)&sh[wave][row][col];
    }

    // attention logits from fp32 accumulators
    const float* a_s = asbase + slot * HID_C;
    const float* a_d = adbase + slot * HID_C;
    float* als = alsbase + (size_t)slot * N_NODES_C * HEADS_C;
    float* ald = aldbase + (size_t)slot * N_NODES_C * HEADS_C;
    float ps[4][4], pd[4][4];
#pragma unroll
    for (int h = 0; h < 4; h++) {
        float as0 = a_s[h * 32 + m], as1 = a_s[h * 32 + 16 + m];
        float ad0 = a_d[h * 32 + m], ad1 = a_d[h * 32 + 16 + m];
#pragma unroll
        for (int i = 0; i < 4; i++) {
            ps[h][i] = acc[2 * h][i] * as0 + acc[2 * h + 1][i] * as1;
            pd[h][i] = acc[2 * h][i] * ad0 + acc[2 * h + 1][i] * ad1;
        }
    }
#pragma unroll
    for (int off = 1; off < 16; off <<= 1) {
#pragma unroll
        for (int h = 0; h < 4; h++)
#pragma unroll
            for (int i = 0; i < 4; i++) {
                ps[h][i] += __shfl_xor(ps[h][i], off);
                pd[h][i] += __shfl_xor(pd[h][i], off);
            }
    }
#pragma unroll
    for (int h = 0; h < 4; h++) {
        if (m == h) {
#pragma unroll
            for (int i = 0; i < 4; i++) {
                int R = r0 + quad * 4 + i;
                if (R < N_NODES_C) {
                    als[R * HEADS_C + h] = ps[h][i];
                    ald[R * HEADS_C + h] = pd[h][i];
                }
            }
        }
    }
}

// ========== fused multi-relation aggregate + bias + softsign + LN ==========
__global__ __launch_bounds__(256) void csr_agg_kernel(
    const int* __restrict__ rowptrP, const int* __restrict__ bsums,
    const int* __restrict__ srcids,
    const __half* __restrict__ A, const float* __restrict__ als,
    const float* __restrict__ ald, int rel_start, int rel_cnt,
    const float* __restrict__ bias, int first, int last,
    float* __restrict__ B,
    const float* __restrict__ g, const float* __restrict__ be,
    __half* __restrict__ Cbh) {
    int node = blockIdx.x * 4 + (threadIdx.x >> 6);
    int lane = threadIdx.x & 63;
    int grp = lane >> 4;
    int j16 = lane & 15;
    int head = j16 >> 2;
    int cbase = j16 * 8;

    float acc[8];
    if (first) {
#pragma unroll
        for (int t = 0; t < 8; t++) {
            float s = 0.f;
#pragma unroll
            for (int r = 0; r < N_REL_C; r++) s += bias[r * HID_C + cbase + t];
            acc[t] = s;
        }
    } else {
        float4 b0 = *(const float4*)(B + (size_t)node * HID_C + cbase);
        float4 b1 = *(const float4*)(B + (size_t)node * HID_C + cbase + 4);
        acc[0] = b0.x; acc[1] = b0.y; acc[2] = b0.z; acc[3] = b0.w;
        acc[4] = b1.x; acc[5] = b1.y; acc[6] = b1.z; acc[7] = b1.w;
    }

    for (int j = 0; j < rel_cnt; j++) {
        int r = rel_start + j;
        const int* rp = rowptrP + (size_t)r * (N_NODES_C + 1);
        const int* bs = bsums + r * NBLK_SCAN;
        const int* sp = srcids + (size_t)r * N_EDGES_C;
        const __half* Aj = A + (size_t)j * N_NODES_C * HID_C;
        const float* alj = als + (size_t)j * N_NODES_C * HEADS_C;
        float aldv = ald[(size_t)j * N_NODES_C * HEADS_C + node * HEADS_C + head];
        int s = rp[node] + bs[node >> 8];
        int e = (node == N_NODES_C - 1) ? N_EDGES_C
                                        : rp[node + 1] + bs[(node + 1) >> 8];
        float racc[8];
#pragma unroll
        for (int t = 0; t < 8; t++) racc[t] = 0.f;
        float rden = 0.f;

        union HU { uint4 u; _Float16 h[8]; };
        int i = s + grp;
        int src = (i < e) ? sp[i] : 0;
        HU rw; rw.u = *(const uint4*)(Aj + (size_t)src * HID_C + cbase);
        float lg = alj[src * HEADS_C + head];
        for (; i < e; i += 4) {
            int nsrc = (i + 4 < e) ? sp[i + 4] : 0;
            HU nrw; nrw.u = *(const uint4*)(Aj + (size_t)nsrc * HID_C + cbase);
            float nlg = alj[nsrc * HEADS_C + head];
            float v = lg + aldv;
            v = fmaxf(v, 0.2f * v);          // leaky_relu
            float ex = __expf(v);
            rden += ex;
#pragma unroll
            for (int t = 0; t < 8; t++)
                racc[t] = fmaf((float)rw.h[t], ex, racc[t]);
            src = nsrc; rw = nrw; lg = nlg;
        }
#pragma unroll
        for (int off = 16; off < 64; off <<= 1) {
            rden += __shfl_xor(rden, off);
#pragma unroll
            for (int t = 0; t < 8; t++) racc[t] += __shfl_xor(racc[t], off);
        }
        float inv = 1.f / (rden + 1e-16f);
#pragma unroll
        for (int t = 0; t < 8; t++) acc[t] = fmaf(racc[t], inv, acc[t]);
    }

    if (!last) {
        if (grp == 0) {
            float4 o0 = make_float4(acc[0], acc[1], acc[2], acc[3]);
            float4 o1 = make_float4(acc[4], acc[5], acc[6], acc[7]);
            *(float4*)(B + (size_t)node * HID_C + cbase) = o0;
            *(float4*)(B + (size_t)node * HID_C + cbase + 4) = o1;
        }
    } else {
        float ss[8];
        float sum = 0.f, sq = 0.f;
#pragma unroll
        for (int t = 0; t < 8; t++) {
            float v = acc[t] / (1.f + fabsf(acc[t]));
            ss[t] = v;
            sum += v;
            sq = fmaf(v, v, sq);
        }
#pragma unroll
        for (int off = 1; off < 16; off <<= 1) {
            sum += __shfl_xor(sum, off);
            sq += __shfl_xor(sq, off);
        }
        float mu = sum * (1.f / 128.f);
        float var = sq * (1.f / 128.f) - mu * mu;
        float inv = rsqrtf(var + 1e-5f);
        if (grp == 0) {
            float4 gv0 = *(const float4*)(g + cbase);
            float4 gv1 = *(const float4*)(g + cbase + 4);
            float4 bv0 = *(const float4*)(be + cbase);
            float4 bv1 = *(const float4*)(be + cbase + 4);
            union { uint4 u; __half2 h2[4]; } ow;
            ow.h2[0] = __float22half2_rn(make_float2(
                (ss[0] - mu) * inv * gv0.x + bv0.x, (ss[1] - mu) * inv * gv0.y + bv0.y));
            ow.h2[1] = __float22half2_rn(make_float2(
                (ss[2] - mu) * inv * gv0.z + bv0.z, (ss[3] - mu) * inv * gv0.w + bv0.w));
            ow.h2[2] = __float22half2_rn(make_float2(
                (ss[4] - mu) * inv * gv1.x + bv1.x, (ss[5] - mu) * inv * gv1.y + bv1.y));
            ow.h2[3] = __float22half2_rn(make_float2(
                (ss[6] - mu) * inv * gv1.z + bv1.z, (ss[7] - mu) * inv * gv1.w + bv1.w));
            *(uint4*)(Cbh + (size_t)node * HID_C + cbase) = ow.u;
        }
    }
}

// ================= fused pooling + projection =================
__device__ __forceinline__ int lower_bound_i(const int* __restrict__ a, int n, int v) {
    int lo = 0, hi = n;
    while (lo < hi) {
        int mid = (lo + hi) >> 1;
        if (a[mid] < v) lo = mid + 1; else hi = mid;
    }
    return lo;
}

// one block (4 waves) per graph: attention-pool into LDS, then project.
__global__ __launch_bounds__(256) void pool_proj_kernel(const __half* __restrict__ H,
                                                        const int* __restrict__ batch,
                                                        const float* __restrict__ q,
                                                        const float* __restrict__ Wp,
                                                        const float* __restrict__ bp,
                                                        float* __restrict__ out) {
    int g = blockIdx.x;
    int t = threadIdx.x;
    int wave = t >> 6, lane = t & 63;
    int start = lower_bound_i(batch, N_NODES_C, g);
    int end = lower_bound_i(batch, N_NODES_C, g + 1);
    float q0 = q[lane * 2], q1 = q[lane * 2 + 1];
    float p0 = 0.f, p1 = 0.f, den = 0.f;
    for (int n = start + wave; n < end; n += 4) {
        float2 hv = __half22float2(*(const __half2*)(H + (size_t)n * HID_C + lane * 2));
        float part = hv.x * q0 + hv.y * q1;
#pragma unroll
        for (int off = 1; off < 64; off <<= 1) part += __shfl_xor(part, off);
        float exs = __expf(part);
        den += exs;
        p0 = fmaf(exs, hv.x, p0);
        p1 = fmaf(exs, hv.y, p1);
    }
    __shared__ float sp[4][HID_C];
    __shared__ float sden[4];
    __shared__ float pl[HID_C];
    sp[wave][lane * 2] = p0;
    sp[wave][lane * 2 + 1] = p1;
    if (lane == 0) sden[wave] = den;
    __syncthreads();
    if (wave == 0) {
        float a0 = sp[0][lane * 2] + sp[1][lane * 2] + sp[2][lane * 2] + sp[3][lane * 2];
        float a1 = sp[0][lane * 2 + 1] + sp[1][lane * 2 + 1] + sp[2][lane * 2 + 1] + sp[3][lane * 2 + 1];
        float d = sden[0] + sden[1] + sden[2] + sden[3];
        float w = 1.f / (d + 1e-16f);
        pl[lane * 2] = a0 * w;
        pl[lane * 2 + 1] = a1 * w;
    }
    __syncthreads();
    if (t < HID_C) {
        float s = bp[t];
        for (int k = 0; k < HID_C; k++) s = fmaf(pl[k], Wp[k * HID_C + t], s);
        out[(size_t)g * HID_C + t] = s;
    }
}

extern "C" void kernel_launch(void* const* d_in, const int* in_sizes, int n_in,
                              void* d_out, int out_size, void* d_ws, size_t ws_size,
                              hipStream_t stream) {
    const float* x   = (const float*)d_in[0];
    const int* ei    = (const int*)d_in[1];
    const int* batch = (const int*)d_in[2];
    const float* W1  = (const float*)d_in[3];
    const float* as1 = (const float*)d_in[4];
    const float* ad1 = (const float*)d_in[5];
    const float* b1  = (const float*)d_in[6];
    const float* W2  = (const float*)d_in[7];
    const float* as2 = (const float*)d_in[8];
    const float* ad2 = (const float*)d_in[9];
    const float* b2  = (const float*)d_in[10];
    const float* g1  = (const float*)d_in[11];
    const float* be1 = (const float*)d_in[12];
    const float* g2  = (const float*)d_in[13];
    const float* be2 = (const float*)d_in[14];
    const float* q   = (const float*)d_in[15];
    const float* Wp  = (const float*)d_in[16];
    const float* bp  = (const float*)d_in[17];
    float* out = (float*)d_out;

    const size_t NH = (size_t)N_NODES_C * HID_C;
    char* w = (char*)d_ws;
    __half* xh    = (__half*)w;   w += (size_t)N_NODES_C * IN_DIM_C * 2;
    __half* Cbh   = (__half*)w;   w += NH * 2;
    __half* Wt1   = (__half*)w;   w += (size_t)N_REL_C * IN_DIM_C * HID_C * 2;
    __half* Wt2   = (__half*)w;   w += (size_t)N_REL_C * HID_C * HID_C * 2;
    int* rowptr   = (int*)w;      w += ((size_t)N_REL_C * (N_NODES_C + 1) * 4 + 15) & ~15ull;
    int* srcids   = (int*)w;      w += (size_t)N_REL_C * N_EDGES_C * 4;
    int* cnt      = (int*)w;      w += (size_t)N_REL_C * N_NODES_C * 4;
    int* bsums    = (int*)w;      w += ((size_t)N_REL_C * NBLK_SCAN * 4 + 15) & ~15ull;

    const size_t fixed_bytes = (size_t)(w - (char*)d_ws);
    const size_t slot_bytes = NH * 2 + 2 * (size_t)N_NODES_C * HEADS_C * 4;
    int nA = 1;
    float* B = nullptr;
    {
        size_t rem = (ws_size > fixed_bytes) ? (ws_size - fixed_bytes) : 0;
        size_t k = rem / slot_bytes;
        if (k >= 6) {
            nA = 6;
        } else {
            size_t rem2 = (rem > NH * 4) ? (rem - NH * 4) : 0;
            size_t k2 = rem2 / slot_bytes;
            nA = (int)(k2 < 1 ? 1 : (k2 > 5 ? 5 : k2));
        }
    }
    float* als = (float*)w;
    float* ald = als + (size_t)nA * N_NODES_C * HEADS_C;
    __half* A  = (__half*)(ald + (size_t)nA * N_NODES_C * HEADS_C);
    if (nA < 6) B = (float*)(A + (size_t)nA * NH);
    // rank[] only live during CSR build, before A is written: alias into A slab
    int* rank = (int*)A;   // 12 MB <= 25.6 MB (first slot)

    // ---- CSR build + converts (fused first pass) ----
    hipMemsetAsync(cnt, 0, (size_t)N_REL_C * N_NODES_C * sizeof(int), stream);
    const int ehg = (N_REL_C * N_EDGES_C + 255) / 256;
    hist_rank_convert_kernel<<<ehg, 256, 0, stream>>>(ei, cnt, rank, x, xh, W1, W2, Wt1, Wt2);
    scan1_kernel<<<dim3(NBLK_SCAN, N_REL_C), 256, 0, stream>>>(cnt, rowptr, bsums);
    scan2_kernel<<<N_REL_C, 512, 0, stream>>>(bsums);
    scatter_kernel<<<ehg, 256, 0, stream>>>(ei, rowptr, bsums, rank, srcids);

    const int gemm_grid = (N_NODES_C + 63) / 64;
    const int agg_grid = N_NODES_C / 4;

    // ---- layer 1 ----
    for (int gs = 0; gs < N_REL_C; gs += nA) {
        int c2 = (N_REL_C - gs) < nA ? (N_REL_C - gs) : nA;
        gemm_mfma_kernel<IN_DIM_C><<<dim3(gemm_grid, c2), 256, 0, stream>>>(
            xh, Wt1 + (size_t)gs * IN_DIM_C * HID_C, A,
            as1 + gs * HID_C, ad1 + gs * HID_C, als, ald);
        csr_agg_kernel<<<agg_grid, 256, 0, stream>>>(
            rowptr, bsums, srcids, A, als, ald, gs, c2,
            b1, (gs == 0) ? 1 : 0, (gs + c2 == N_REL_C) ? 1 : 0,
            B, g1, be1, Cbh);
    }
    // ---- layer 2 ----
    for (int gs = 0; gs < N_REL_C; gs += nA) {
        int c2 = (N_REL_C - gs) < nA ? (N_REL_C - gs) : nA;
        gemm_mfma_kernel<HID_C><<<dim3(gemm_grid, c2), 256, 0, stream>>>(
            Cbh, Wt2 + (size_t)gs * HID_C * HID_C, A,
            as2 + gs * HID_C, ad2 + gs * HID_C, als, ald);
        csr_agg_kernel<<<agg_grid, 256, 0, stream>>>(
            rowptr, bsums, srcids, A, als, ald, gs, c2,
            b2, (gs == 0) ? 1 : 0, (gs + c2 == N_REL_C) ? 1 : 0,
            B, g2, be2, Cbh);
    }

    // ---- fused pooling + projection ----
    pool_proj_kernel<<<N_GRAPHS_C, 256, 0, stream>>>(Cbh, batch, q, Wp, bp, out);
}

// Round 12
// 1041.807 us; speedup vs baseline: 1.0202x; 1.0202x over previous
//
#include <hip/hip_runtime.h>
#include <hip/hip_bf16.h>
#include <hip/hip_fp16.h>

#define N_NODES_C 100000
#define N_EDGES_C 500000
#define N_REL_C 6
#define IN_DIM_C 64
#define HID_C 128
#define HEADS_C 4
#define CPH_C 32
#define N_GRAPHS_C 1024
#define NBLK_SCAN 391   // ceil(100000/256)
#define SH_PAD 8        // LDS transpose row pad (halves): 2-way banks, 16B aligned

typedef _Float16 f16x8 __attribute__((ext_vector_type(8)));
typedef float f32x4 __attribute__((ext_vector_type(4)));

// ========== CSR hist+rank, fused with fp32->fp16 converts ==========
__global__ __launch_bounds__(256) void hist_rank_convert_kernel(
    const int* __restrict__ ei, int* __restrict__ cnt, int* __restrict__ rank,
    const float* __restrict__ x, __half* __restrict__ xh,
    const float* __restrict__ W1, const float* __restrict__ W2,
    __half* __restrict__ Wt1, __half* __restrict__ Wt2) {
    int i = blockIdx.x * 256 + threadIdx.x;
    // convert x (1.6M float4 groups)
    if (i < N_NODES_C * IN_DIM_C / 4) {
        float4 v = ((const float4*)x)[i];
        union { __half h[4]; uint2 u; } u;
        u.h[0] = __float2half(v.x); u.h[1] = __float2half(v.y);
        u.h[2] = __float2half(v.z); u.h[3] = __float2half(v.w);
        ((uint2*)xh)[i] = u.u;
    }
    // convert + transpose W1, W2
    if (i < N_REL_C * IN_DIM_C * HID_C) {
        int r = i / (IN_DIM_C * HID_C);
        int rem = i - r * (IN_DIM_C * HID_C);
        int k = rem / HID_C, n = rem - k * HID_C;
        Wt1[(size_t)r * HID_C * IN_DIM_C + n * IN_DIM_C + k] = __float2half(W1[i]);
    }
    if (i < N_REL_C * HID_C * HID_C) {
        int r = i / (HID_C * HID_C);
        int rem = i - r * (HID_C * HID_C);
        int k = rem / HID_C, n = rem - k * HID_C;
        Wt2[(size_t)r * HID_C * HID_C + n * HID_C + k] = __float2half(W2[i]);
    }
    // histogram + per-edge rank
    if (i < N_REL_C * N_EDGES_C) {
        int r = i / N_EDGES_C;
        int e = i - r * N_EDGES_C;
        int dst = ei[(size_t)r * 2 * N_EDGES_C + N_EDGES_C + e];
        rank[i] = atomicAdd(&cnt[r * N_NODES_C + dst], 1);
    }
}

// per-256-block exclusive scan; bsums[r][b] = block total
__global__ __launch_bounds__(256) void scan1_kernel(const int* __restrict__ cnt,
                                                    int* __restrict__ rowptr,
                                                    int* __restrict__ blocksums) {
    int r = blockIdx.y, b = blockIdx.x, t = threadIdx.x;
    int idx = b * 256 + t;
    int v = (idx < N_NODES_C) ? cnt[r * N_NODES_C + idx] : 0;
    int orig = v;
    int lane = t & 63, w = t >> 6;
#pragma unroll
    for (int off = 1; off < 64; off <<= 1) {
        int n = __shfl_up(v, off);
        if (lane >= off) v += n;
    }
    __shared__ int wt[4];
    if (lane == 63) wt[w] = v;
    __syncthreads();
    int add = 0;
    for (int i = 0; i < w; i++) add += wt[i];
    v += add;
    if (idx < N_NODES_C) rowptr[(size_t)r * (N_NODES_C + 1) + idx] = v - orig;
    if (t == 255) blocksums[r * NBLK_SCAN + b] = v;
}

// scan block sums -> exclusive prefixes (final rowptr = rowptrP + bsums[b])
__global__ __launch_bounds__(512) void scan2_kernel(int* __restrict__ blocksums) {
    int r = blockIdx.x, t = threadIdx.x;
    int v = (t < NBLK_SCAN) ? blocksums[r * NBLK_SCAN + t] : 0;
    int orig = v;
    int lane = t & 63, w = t >> 6;
#pragma unroll
    for (int off = 1; off < 64; off <<= 1) {
        int n = __shfl_up(v, off);
        if (lane >= off) v += n;
    }
    __shared__ int wt[8];
    if (lane == 63) wt[w] = v;
    __syncthreads();
    int add = 0;
    for (int i = 0; i < w; i++) add += wt[i];
    v += add;
    if (t < NBLK_SCAN) blocksums[r * NBLK_SCAN + t] = v - orig;
}

// atomic-free scatter; final rowptr computed inline
__global__ __launch_bounds__(256) void scatter_kernel(const int* __restrict__ ei,
                                                      const int* __restrict__ rowptrP,
                                                      const int* __restrict__ bsums,
                                                      const int* __restrict__ rank,
                                                      int* __restrict__ srcids) {
    int i = blockIdx.x * 256 + threadIdx.x;
    if (i >= N_REL_C * N_EDGES_C) return;
    int r = i / N_EDGES_C;
    int e = i - r * N_EDGES_C;
    int src = ei[(size_t)r * 2 * N_EDGES_C + e];
    int dst = ei[(size_t)r * 2 * N_EDGES_C + N_EDGES_C + e];
    int base = rowptrP[(size_t)r * (N_NODES_C + 1) + dst] + bsums[r * NBLK_SCAN + (dst >> 8)];
    srcids[(size_t)r * N_EDGES_C + base + rank[i]] = src;
}

// ================= fp16 MFMA GEMM + attn-logit epilogue =================
// grid.y = relation slot; LDS transpose buffer padded (bank-conflict-free).
template <int K>
__global__ __launch_bounds__(256) void gemm_mfma_kernel(
    const __half* __restrict__ Xh, const __half* __restrict__ Wtbase,
    __half* __restrict__ Hbase,
    const float* __restrict__ asbase, const float* __restrict__ adbase,
    float* __restrict__ alsbase, float* __restrict__ aldbase) {
    __shared__ _Float16 sh[4][16][HID_C + SH_PAD];
    const int slot = blockIdx.y;
    const __half* Wt = Wtbase + (size_t)slot * HID_C * K;
    __half* H = Hbase + (size_t)slot * N_NODES_C * HID_C;
    const int wave = threadIdx.x >> 6, lane = threadIdx.x & 63;
    const int r0 = blockIdx.x * 64 + wave * 16;
    const int m = lane & 15, quad = lane >> 4;
    int arow = r0 + m;
    if (arow > N_NODES_C - 1) arow = N_NODES_C - 1;
    const __half* ap = Xh + (size_t)arow * K + quad * 8;
    const __half* bp = Wt + (size_t)m * K + quad * 8;

    f32x4 acc[8];
#pragma unroll
    for (int t = 0; t < 8; t++) acc[t] = (f32x4){0.f, 0.f, 0.f, 0.f};

#pragma unroll
    for (int kc = 0; kc < K; kc += 32) {
        f16x8 a = *(const f16x8*)(ap + kc);
#pragma unroll
        for (int t = 0; t < 8; t++) {
            f16x8 b = *(const f16x8*)(bp + (size_t)t * 16 * K + kc);
            acc[t] = __builtin_amdgcn_mfma_f32_16x16x32_f16(a, b, acc[t], 0, 0, 0);
        }
    }

    // transpose C-layout -> row-major via LDS (same-wave: no barrier needed)
#pragma unroll
    for (int t = 0; t < 8; t++)
#pragma unroll
        for (int i = 0; i < 4; i++)
            sh[wave][quad * 4 + i][t * 16 + m] = (_Float16)acc[t][i];
#pragma unroll
    for (int p = 0; p < 4; p++) {
        int idx = p * 512 + lane * 8;
        int row = idx >> 7;
        int col = idx & 127;
        int R = r0 + row;
        if (R < N_NODES_C)
            *(uint4*)(H + (size_t)R * HID_C + col) = *(const uint4*)&sh[wave][row][col];
    }

    // attention logits from fp32 accumulators
    const float* a_s = asbase + slot * HID_C;
    const float* a_d = adbase + slot * HID_C;
    float* als = alsbase + (size_t)slot * N_NODES_C * HEADS_C;
    float* ald = aldbase + (size_t)slot * N_NODES_C * HEADS_C;
    float ps[4][4], pd[4][4];
#pragma unroll
    for (int h = 0; h < 4; h++) {
        float as0 = a_s[h * 32 + m], as1 = a_s[h * 32 + 16 + m];
        float ad0 = a_d[h * 32 + m], ad1 = a_d[h * 32 + 16 + m];
#pragma unroll
        for (int i = 0; i < 4; i++) {
            ps[h][i] = acc[2 * h][i] * as0 + acc[2 * h + 1][i] * as1;
            pd[h][i] = acc[2 * h][i] * ad0 + acc[2 * h + 1][i] * ad1;
        }
    }
#pragma unroll
    for (int off = 1; off < 16; off <<= 1) {
#pragma unroll
        for (int h = 0; h < 4; h++)
#pragma unroll
            for (int i = 0; i < 4; i++) {
                ps[h][i] += __shfl_xor(ps[h][i], off);
                pd[h][i] += __shfl_xor(pd[h][i], off);
            }
    }
#pragma unroll
    for (int h = 0; h < 4; h++) {
        if (m == h) {
#pragma unroll
            for (int i = 0; i < 4; i++) {
                int R = r0 + quad * 4 + i;
                if (R < N_NODES_C) {
                    als[R * HEADS_C + h] = ps[h][i];
                    ald[R * HEADS_C + h] = pd[h][i];
                }
            }
        }
    }
}

// ========== fused multi-relation aggregate + bias + softsign + LN ==========
__global__ __launch_bounds__(256) void csr_agg_kernel(
    const int* __restrict__ rowptrP, const int* __restrict__ bsums,
    const int* __restrict__ srcids,
    const __half* __restrict__ A, const float* __restrict__ als,
    const float* __restrict__ ald, int rel_start, int rel_cnt,
    const float* __restrict__ bias, int first, int last,
    float* __restrict__ B,
    const float* __restrict__ g, const float* __restrict__ be,
    __half* __restrict__ Cbh) {
    int node = blockIdx.x * 4 + (threadIdx.x >> 6);
    int lane = threadIdx.x & 63;
    int grp = lane >> 4;
    int j16 = lane & 15;
    int head = j16 >> 2;
    int cbase = j16 * 8;

    float acc[8];
    if (first) {
#pragma unroll
        for (int t = 0; t < 8; t++) {
            float s = 0.f;
#pragma unroll
            for (int r = 0; r < N_REL_C; r++) s += bias[r * HID_C + cbase + t];
            acc[t] = s;
        }
    } else {
        float4 b0 = *(const float4*)(B + (size_t)node * HID_C + cbase);
        float4 b1 = *(const float4*)(B + (size_t)node * HID_C + cbase + 4);
        acc[0] = b0.x; acc[1] = b0.y; acc[2] = b0.z; acc[3] = b0.w;
        acc[4] = b1.x; acc[5] = b1.y; acc[6] = b1.z; acc[7] = b1.w;
    }

    for (int j = 0; j < rel_cnt; j++) {
        int r = rel_start + j;
        const int* rp = rowptrP + (size_t)r * (N_NODES_C + 1);
        const int* bs = bsums + r * NBLK_SCAN;
        const int* sp = srcids + (size_t)r * N_EDGES_C;
        const __half* Aj = A + (size_t)j * N_NODES_C * HID_C;
        const float* alj = als + (size_t)j * N_NODES_C * HEADS_C;
        float aldv = ald[(size_t)j * N_NODES_C * HEADS_C + node * HEADS_C + head];
        int s = rp[node] + bs[node >> 8];
        int e = (node == N_NODES_C - 1) ? N_EDGES_C
                                        : rp[node + 1] + bs[(node + 1) >> 8];
        float racc[8];
#pragma unroll
        for (int t = 0; t < 8; t++) racc[t] = 0.f;
        float rden = 0.f;

        union HU { uint4 u; _Float16 h[8]; };
        int i = s + grp;
        int src = (i < e) ? sp[i] : 0;
        HU rw; rw.u = *(const uint4*)(Aj + (size_t)src * HID_C + cbase);
        float lg = alj[src * HEADS_C + head];
        for (; i < e; i += 4) {
            int nsrc = (i + 4 < e) ? sp[i + 4] : 0;
            HU nrw; nrw.u = *(const uint4*)(Aj + (size_t)nsrc * HID_C + cbase);
            float nlg = alj[nsrc * HEADS_C + head];
            float v = lg + aldv;
            v = fmaxf(v, 0.2f * v);          // leaky_relu
            float ex = __expf(v);
            rden += ex;
#pragma unroll
            for (int t = 0; t < 8; t++)
                racc[t] = fmaf((float)rw.h[t], ex, racc[t]);
            src = nsrc; rw = nrw; lg = nlg;
        }
#pragma unroll
        for (int off = 16; off < 64; off <<= 1) {
            rden += __shfl_xor(rden, off);
#pragma unroll
            for (int t = 0; t < 8; t++) racc[t] += __shfl_xor(racc[t], off);
        }
        float inv = 1.f / (rden + 1e-16f);
#pragma unroll
        for (int t = 0; t < 8; t++) acc[t] = fmaf(racc[t], inv, acc[t]);
    }

    if (!last) {
        if (grp == 0) {
            float4 o0 = make_float4(acc[0], acc[1], acc[2], acc[3]);
            float4 o1 = make_float4(acc[4], acc[5], acc[6], acc[7]);
            *(float4*)(B + (size_t)node * HID_C + cbase) = o0;
            *(float4*)(B + (size_t)node * HID_C + cbase + 4) = o1;
        }
    } else {
        float ss[8];
        float sum = 0.f, sq = 0.f;
#pragma unroll
        for (int t = 0; t < 8; t++) {
            float v = acc[t] / (1.f + fabsf(acc[t]));
            ss[t] = v;
            sum += v;
            sq = fmaf(v, v, sq);
        }
#pragma unroll
        for (int off = 1; off < 16; off <<= 1) {
            sum += __shfl_xor(sum, off);
            sq += __shfl_xor(sq, off);
        }
        float mu = sum * (1.f / 128.f);
        float var = sq * (1.f / 128.f) - mu * mu;
        float inv = rsqrtf(var + 1e-5f);
        if (grp == 0) {
            float4 gv0 = *(const float4*)(g + cbase);
            float4 gv1 = *(const float4*)(g + cbase + 4);
            float4 bv0 = *(const float4*)(be + cbase);
            float4 bv1 = *(const float4*)(be + cbase + 4);
            union { uint4 u; __half2 h2[4]; } ow;
            ow.h2[0] = __float22half2_rn(make_float2(
                (ss[0] - mu) * inv * gv0.x + bv0.x, (ss[1] - mu) * inv * gv0.y + bv0.y));
            ow.h2[1] = __float22half2_rn(make_float2(
                (ss[2] - mu) * inv * gv0.z + bv0.z, (ss[3] - mu) * inv * gv0.w + bv0.w));
            ow.h2[2] = __float22half2_rn(make_float2(
                (ss[4] - mu) * inv * gv1.x + bv1.x, (ss[5] - mu) * inv * gv1.y + bv1.y));
            ow.h2[3] = __float22half2_rn(make_float2(
                (ss[6] - mu) * inv * gv1.z + bv1.z, (ss[7] - mu) * inv * gv1.w + bv1.w));
            *(uint4*)(Cbh + (size_t)node * HID_C + cbase) = ow.u;
        }
    }
}

// ================= pooling + projection =================
__device__ __forceinline__ int lower_bound_i(const int* __restrict__ a, int n, int v) {
    int lo = 0, hi = n;
    while (lo < hi) {
        int mid = (lo + hi) >> 1;
        if (a[mid] < v) lo = mid + 1; else hi = mid;
    }
    return lo;
}

__global__ __launch_bounds__(256) void pool_kernel(const __half* __restrict__ H,
                                                   const int* __restrict__ batch,
                                                   const float* __restrict__ q,
                                                   float* __restrict__ pooled) {
    int g = blockIdx.x;
    int t = threadIdx.x;
    int wave = t >> 6, lane = t & 63;
    int start = lower_bound_i(batch, N_NODES_C, g);
    int end = lower_bound_i(batch, N_NODES_C, g + 1);
    float q0 = q[lane * 2], q1 = q[lane * 2 + 1];
    float p0 = 0.f, p1 = 0.f, den = 0.f;
    for (int n = start + wave; n < end; n += 4) {
        float2 hv = __half22float2(*(const __half2*)(H + (size_t)n * HID_C + lane * 2));
        float part = hv.x * q0 + hv.y * q1;
#pragma unroll
        for (int off = 1; off < 64; off <<= 1) part += __shfl_xor(part, off);
        float exs = __expf(part);
        den += exs;
        p0 = fmaf(exs, hv.x, p0);
        p1 = fmaf(exs, hv.y, p1);
    }
    __shared__ float sp[4][HID_C];
    __shared__ float sden[4];
    sp[wave][lane * 2] = p0;
    sp[wave][lane * 2 + 1] = p1;
    if (lane == 0) sden[wave] = den;
    __syncthreads();
    if (wave == 0) {
        float a0 = sp[0][lane * 2] + sp[1][lane * 2] + sp[2][lane * 2] + sp[3][lane * 2];
        float a1 = sp[0][lane * 2 + 1] + sp[1][lane * 2 + 1] + sp[2][lane * 2 + 1] + sp[3][lane * 2 + 1];
        float d = sden[0] + sden[1] + sden[2] + sden[3];
        float w = 1.f / (d + 1e-16f);
        pooled[(size_t)g * HID_C + lane * 2] = a0 * w;
        pooled[(size_t)g * HID_C + lane * 2 + 1] = a1 * w;
    }
}

__global__ __launch_bounds__(128) void proj_kernel(const float* __restrict__ pooled,
                                                   const float* __restrict__ Wp,
                                                   const float* __restrict__ bp,
                                                   float* __restrict__ out) {
    int g = blockIdx.x, c = threadIdx.x;
    __shared__ float pl[HID_C];
    pl[c] = pooled[(size_t)g * HID_C + c];
    __syncthreads();
    float s = bp[c];
    for (int k = 0; k < HID_C; k++) s = fmaf(pl[k], Wp[k * HID_C + c], s);
    out[(size_t)g * HID_C + c] = s;
}

extern "C" void kernel_launch(void* const* d_in, const int* in_sizes, int n_in,
                              void* d_out, int out_size, void* d_ws, size_t ws_size,
                              hipStream_t stream) {
    const float* x   = (const float*)d_in[0];
    const int* ei    = (const int*)d_in[1];
    const int* batch = (const int*)d_in[2];
    const float* W1  = (const float*)d_in[3];
    const float* as1 = (const float*)d_in[4];
    const float* ad1 = (const float*)d_in[5];
    const float* b1  = (const float*)d_in[6];
    const float* W2  = (const float*)d_in[7];
    const float* as2 = (const float*)d_in[8];
    const float* ad2 = (const float*)d_in[9];
    const float* b2  = (const float*)d_in[10];
    const float* g1  = (const float*)d_in[11];
    const float* be1 = (const float*)d_in[12];
    const float* g2  = (const float*)d_in[13];
    const float* be2 = (const float*)d_in[14];
    const float* q   = (const float*)d_in[15];
    const float* Wp  = (const float*)d_in[16];
    const float* bp  = (const float*)d_in[17];
    float* out = (float*)d_out;

    const size_t NH = (size_t)N_NODES_C * HID_C;
    char* w = (char*)d_ws;
    __half* xh    = (__half*)w;   w += (size_t)N_NODES_C * IN_DIM_C * 2;
    __half* Cbh   = (__half*)w;   w += NH * 2;
    __half* Wt1   = (__half*)w;   w += (size_t)N_REL_C * IN_DIM_C * HID_C * 2;
    __half* Wt2   = (__half*)w;   w += (size_t)N_REL_C * HID_C * HID_C * 2;
    float* pooled = (float*)w;    w += (size_t)N_GRAPHS_C * HID_C * 4;
    int* rowptr   = (int*)w;      w += ((size_t)N_REL_C * (N_NODES_C + 1) * 4 + 15) & ~15ull;
    int* srcids   = (int*)w;      w += (size_t)N_REL_C * N_EDGES_C * 4;
    int* cnt      = (int*)w;      w += (size_t)N_REL_C * N_NODES_C * 4;
    int* bsums    = (int*)w;      w += ((size_t)N_REL_C * NBLK_SCAN * 4 + 15) & ~15ull;

    const size_t fixed_bytes = (size_t)(w - (char*)d_ws);
    const size_t slot_bytes = NH * 2 + 2 * (size_t)N_NODES_C * HEADS_C * 4;
    int nA = 1;
    float* B = nullptr;
    {
        size_t rem = (ws_size > fixed_bytes) ? (ws_size - fixed_bytes) : 0;
        size_t k = rem / slot_bytes;
        if (k >= 6) {
            nA = 6;
        } else {
            size_t rem2 = (rem > NH * 4) ? (rem - NH * 4) : 0;
            size_t k2 = rem2 / slot_bytes;
            nA = (int)(k2 < 1 ? 1 : (k2 > 5 ? 5 : k2));
        }
    }
    float* als = (float*)w;
    float* ald = als + (size_t)nA * N_NODES_C * HEADS_C;
    __half* A  = (__half*)(ald + (size_t)nA * N_NODES_C * HEADS_C);
    if (nA < 6) B = (float*)(A + (size_t)nA * NH);
    // rank[] only live during CSR build, before A is written: alias into A slab
    int* rank = (int*)A;   // 12 MB <= 25.6 MB (first slot)

    // ---- CSR build + converts (fused first pass) ----
    hipMemsetAsync(cnt, 0, (size_t)N_REL_C * N_NODES_C * sizeof(int), stream);
    const int ehg = (N_REL_C * N_EDGES_C + 255) / 256;
    hist_rank_convert_kernel<<<ehg, 256, 0, stream>>>(ei, cnt, rank, x, xh, W1, W2, Wt1, Wt2);
    scan1_kernel<<<dim3(NBLK_SCAN, N_REL_C), 256, 0, stream>>>(cnt, rowptr, bsums);
    scan2_kernel<<<N_REL_C, 512, 0, stream>>>(bsums);
    scatter_kernel<<<ehg, 256, 0, stream>>>(ei, rowptr, bsums, rank, srcids);

    const int gemm_grid = (N_NODES_C + 63) / 64;
    const int agg_grid = N_NODES_C / 4;

    // ---- layer 1 ----
    for (int gs = 0; gs < N_REL_C; gs += nA) {
        int c2 = (N_REL_C - gs) < nA ? (N_REL_C - gs) : nA;
        gemm_mfma_kernel<IN_DIM_C><<<dim3(gemm_grid, c2), 256, 0, stream>>>(
            xh, Wt1 + (size_t)gs * IN_DIM_C * HID_C, A,
            as1 + gs * HID_C, ad1 + gs * HID_C, als, ald);
        csr_agg_kernel<<<agg_grid, 256, 0, stream>>>(
            rowptr, bsums, srcids, A, als, ald, gs, c2,
            b1, (gs == 0) ? 1 : 0, (gs + c2 == N_REL_C) ? 1 : 0,
            B, g1, be1, Cbh);
    }
    // ---- layer 2 ----
    for (int gs = 0; gs < N_REL_C; gs += nA) {
        int c2 = (N_REL_C - gs) < nA ? (N_REL_C - gs) : nA;
        gemm_mfma_kernel<HID_C><<<dim3(gemm_grid, c2), 256, 0, stream>>>(
            Cbh, Wt2 + (size_t)gs * HID_C * HID_C, A,
            as2 + gs * HID_C, ad2 + gs * HID_C, als, ald);
        csr_agg_kernel<<<agg_grid, 256, 0, stream>>>(
            rowptr, bsums, srcids, A, als, ald, gs, c2,
            b2, (gs == 0) ? 1 : 0, (gs + c2 == N_REL_C) ? 1 : 0,
            B, g2, be2, Cbh);
    }

    // ---- pooling + projection ----
    pool_kernel<<<N_GRAPHS_C, 256, 0, stream>>>(Cbh, batch, q, pooled);
    proj_kernel<<<N_GRAPHS_C, 128, 0, stream>>>(pooled, Wp, bp, out);
}